// Round 1
// baseline (132.073 us; speedup 1.0000x reference)
//
#include <hip/hip_runtime.h>

// MaskLayer: inputs [B=512, H=14, W=14, C=512] fp32, channel-innermost.
// Per (b,c): rows_idx = argmax_h(max_w x), cols_idx = argmax_w(max_h x).
// out = max(TAU * max(1 - (BETA/IMG)*(|h-ri|+|w-ci|), -1) * x, 0).

typedef float f32x2 __attribute__((ext_vector_type(2)));

#define IMG 14
#define C2  256  // 512 channels / 2 per thread (float2)

__global__ __launch_bounds__(256)
void mask_kernel(const f32x2* __restrict__ in, f32x2* __restrict__ out) {
    const int b  = blockIdx.x;    // one sample per block
    const int c2 = threadIdx.x;   // channel-pair index 0..255
    const size_t base_off = (size_t)b * (IMG * IMG * C2) + c2;
    const f32x2* __restrict__ bin  = in  + base_off;
    f32x2* __restrict__       bout = out + base_off;

    // ---- pass 1: row maxes (max over w) and col maxes (max over h) ----
    float rmx[IMG], rmy[IMG], cmx[IMG], cmy[IMG];
#pragma unroll
    for (int w = 0; w < IMG; ++w) {
        cmx[w] = -__builtin_inff();
        cmy[w] = -__builtin_inff();
    }
#pragma unroll
    for (int h = 0; h < IMG; ++h) {
        float mx = -__builtin_inff(), my = -__builtin_inff();
#pragma unroll
        for (int w = 0; w < IMG; ++w) {
            f32x2 v = bin[(h * IMG + w) * C2];   // coalesced: lanes = channels
            mx = fmaxf(mx, v.x);
            my = fmaxf(my, v.y);
            cmx[w] = fmaxf(cmx[w], v.x);
            cmy[w] = fmaxf(cmy[w], v.y);
        }
        rmx[h] = mx;
        rmy[h] = my;
    }

    // ---- first-occurrence argmax (strict >, matches jnp.argmax) ----
    int rix = 0, riy = 0, cix = 0, ciy = 0;
    float bx = rmx[0], by = rmy[0];
#pragma unroll
    for (int h = 1; h < IMG; ++h) {
        if (rmx[h] > bx) { bx = rmx[h]; rix = h; }
        if (rmy[h] > by) { by = rmy[h]; riy = h; }
    }
    bx = cmx[0]; by = cmy[0];
#pragma unroll
    for (int w = 1; w < IMG; ++w) {
        if (cmx[w] > bx) { bx = cmx[w]; cix = w; }
        if (cmy[w] > by) { by = cmy[w]; ciy = w; }
    }

    // ---- pass 2: apply mask; reload hits L2/L3 ----
    const float k   = (float)(4.0 / 14.0);          // BETA / IMG as f32
    const float tau = (float)(0.5 / (14.0 * 14.0)); // TAU as f32
#pragma unroll
    for (int h = 0; h < IMG; ++h) {
        int drx = h - rix; drx = drx < 0 ? -drx : drx;
        int dry = h - riy; dry = dry < 0 ? -dry : dry;
#pragma unroll
        for (int w = 0; w < IMG; ++w) {
            f32x2 v = bin[(h * IMG + w) * C2];
            int dcx = w - cix; dcx = dcx < 0 ? -dcx : dcx;
            int dcy = w - ciy; dcy = dcy < 0 ? -dcy : dcy;
            // (TAU * clamp) * x — same association as reference
            float wx = fmaxf(1.0f - k * (float)(drx + dcx), -1.0f) * tau;
            float wy = fmaxf(1.0f - k * (float)(dry + dcy), -1.0f) * tau;
            f32x2 o;
            o.x = fmaxf(wx * v.x, 0.0f);
            o.y = fmaxf(wy * v.y, 0.0f);
            // non-temporal: don't let the write stream evict cached input
            __builtin_nontemporal_store(o, &bout[(h * IMG + w) * C2]);
        }
    }
}

extern "C" void kernel_launch(void* const* d_in, const int* in_sizes, int n_in,
                              void* d_out, int out_size, void* d_ws, size_t ws_size,
                              hipStream_t stream) {
    const f32x2* in  = (const f32x2*)d_in[0];
    f32x2*       out = (f32x2*)d_out;
    // B = 512 blocks, 256 threads = 256 channel-pairs each
    mask_kernel<<<512, 256, 0, stream>>>(in, out);
}

// Round 2
// 93.201 us; speedup vs baseline: 1.4171x; 1.4171x over previous
//
#include <hip/hip_runtime.h>

// MaskLayer: inputs [B=512, H=14, W=14, C=512] fp32, channel-innermost.
// Per (b,c): rows_idx = argmax_h(max_w x), cols_idx = argmax_w(max_h x).
// out = max(TAU * max(1 - (BETA/IMG)*(|h-ri|+|w-ci|), -1) * x, 0).
//
// Parallelization: 4 lanes cooperate per (b, channel-pair).
//   lane = tid & 63;  hg = lane >> 4 (row-group 0..3);  c2_lo = lane & 15.
//   Row groups: {0-3, 4-7, 8-10, 11-13}. Merges via __shfl_xor(16/32),
//   fully intra-wave -> no LDS, no barriers.
// Grid: 512 samples x 4 channel-quarters = 2048 blocks x 256 thr = 8192 waves.

typedef float f32x2 __attribute__((ext_vector_type(2)));

#define IMG 14
#define C2  256  // channel-pairs per sample (512 ch / 2)

__global__ __launch_bounds__(256)
void mask_kernel(const f32x2* __restrict__ in, f32x2* __restrict__ out) {
    const int b    = blockIdx.x >> 2;         // sample
    const int quad = blockIdx.x & 3;          // channel quarter
    const int lane = threadIdx.x & 63;
    const int wv   = threadIdx.x >> 6;        // wave within block (0..3)
    const int hg   = lane >> 4;               // row group 0..3
    const int c2   = quad * 64 + wv * 16 + (lane & 15);

    const int rstart = (hg < 2) ? hg * 4 : 8 + (hg - 2) * 3;
    const int rcnt   = (hg < 2) ? 4 : 3;

    const size_t base_off = (size_t)b * (IMG * IMG * C2) + c2;
    const f32x2* __restrict__ bin  = in  + base_off;
    f32x2* __restrict__       bout = out + base_off;

    const float NINF = -__builtin_inff();

    // ---- pass 1: partial row/col maxes over this lane's rows ----
    float cmx[IMG], cmy[IMG];
#pragma unroll
    for (int w = 0; w < IMG; ++w) { cmx[w] = NINF; cmy[w] = NINF; }

    float rbx = NINF, rby = NINF;   // best row-max value
    int   rix = 0,    riy = 0;      // its row index
    for (int r = rstart; r < rstart + rcnt; ++r) {
        float mx = NINF, my = NINF;
#pragma unroll
        for (int w = 0; w < IMG; ++w) {
            f32x2 v = bin[(r * IMG + w) * C2];
            mx = fmaxf(mx, v.x);
            my = fmaxf(my, v.y);
            cmx[w] = fmaxf(cmx[w], v.x);
            cmy[w] = fmaxf(cmy[w], v.y);
        }
        if (mx > rbx) { rbx = mx; rix = r; }
        if (my > rby) { rby = my; riy = r; }
    }

    // ---- merge row-argmax across the 4 row-groups (xor 16, 32) ----
    // rule: larger value wins; tie -> smaller row index (= first occurrence)
#pragma unroll
    for (int s = 16; s <= 32; s <<= 1) {
        float ovx = __shfl_xor(rbx, s, 64);
        int   oix = __shfl_xor(rix, s, 64);
        if (ovx > rbx || (ovx == rbx && oix < rix)) { rbx = ovx; rix = oix; }
        float ovy = __shfl_xor(rby, s, 64);
        int   oiy = __shfl_xor(riy, s, 64);
        if (ovy > rby || (ovy == rby && oiy < riy)) { rby = ovy; riy = oiy; }
    }

    // ---- merge col maxes across the 4 row-groups ----
#pragma unroll
    for (int w = 0; w < IMG; ++w) {
        cmx[w] = fmaxf(cmx[w], __shfl_xor(cmx[w], 16, 64));
        cmx[w] = fmaxf(cmx[w], __shfl_xor(cmx[w], 32, 64));
        cmy[w] = fmaxf(cmy[w], __shfl_xor(cmy[w], 16, 64));
        cmy[w] = fmaxf(cmy[w], __shfl_xor(cmy[w], 32, 64));
    }

    // ---- col argmax (first occurrence) ----
    int cix = 0, ciy = 0;
    float bx = cmx[0], by = cmy[0];
#pragma unroll
    for (int w = 1; w < IMG; ++w) {
        if (cmx[w] > bx) { bx = cmx[w]; cix = w; }
        if (cmy[w] > by) { by = cmy[w]; ciy = w; }
    }

    // ---- pass 2: apply mask to own rows; reload hits L2/L3 ----
    const float k   = (float)(4.0 / 14.0);          // BETA / IMG
    const float tau = (float)(0.5 / (14.0 * 14.0)); // TAU
    for (int r = rstart; r < rstart + rcnt; ++r) {
        int drx = r - rix; drx = drx < 0 ? -drx : drx;
        int dry = r - riy; dry = dry < 0 ? -dry : dry;
#pragma unroll
        for (int w = 0; w < IMG; ++w) {
            f32x2 v = bin[(r * IMG + w) * C2];
            int dcx = w - cix; dcx = dcx < 0 ? -dcx : dcx;
            int dcy = w - ciy; dcy = dcy < 0 ? -dcy : dcy;
            float wx = fmaxf(1.0f - k * (float)(drx + dcx), -1.0f) * tau;
            float wy = fmaxf(1.0f - k * (float)(dry + dcy), -1.0f) * tau;
            f32x2 o;
            o.x = fmaxf(wx * v.x, 0.0f);
            o.y = fmaxf(wy * v.y, 0.0f);
            __builtin_nontemporal_store(o, &bout[(r * IMG + w) * C2]);
        }
    }
}

extern "C" void kernel_launch(void* const* d_in, const int* in_sizes, int n_in,
                              void* d_out, int out_size, void* d_ws, size_t ws_size,
                              hipStream_t stream) {
    const f32x2* in  = (const f32x2*)d_in[0];
    f32x2*       out = (f32x2*)d_out;
    // 512 samples x 4 channel-quarters; 256 threads = 4 waves x (16 c2 x 4 hg)
    mask_kernel<<<512 * 4, 256, 0, stream>>>(in, out);
}